// Round 1
// baseline (2648.968 us; speedup 1.0000x reference)
//
#include <hip/hip_runtime.h>
#include <math.h>

#define B 32
#define NS 384
#define H 6
#define DH 64
#define LAYERS 4
#define CACHE_T 447
#define SELF_T 448
#define CROSS_T 1500
#define VOCAB 51865
#define SCALE 0.125f

// ---------------------------------------------------------------------------
// ws layout (floats):
//   xbuf  @ 0       [32][384]   residual stream x
//   xlnT  @ 12288   [384][32]   LN output, TRANSPOSED (d-major) for scalar loads
//   qbuf  @ 24576   [32][384]   q projection
//   oT    @ 36864   [384][32]   attention output, transposed
//   h1T   @ 49152   [1536][32]  MLP hidden, transposed
//   po    @ 98304   [32][6][6][64]  flash partial O
//   pml   @ 172032  [32][6][6][2]   flash partial (m, l)
// total 174,336 floats = 697 KB
// ---------------------------------------------------------------------------

__global__ void copy_te_kernel(const float* __restrict__ te, float* __restrict__ xbuf) {
    int i = blockIdx.x * 256 + threadIdx.x;
    if (i < B * NS) xbuf[i] = te[i];
}

// copies self_k/self_v caches (rows 0..446) into the output new_ks/new_vs regions
__global__ void copy_cache_kernel(const float* __restrict__ k0, const float* __restrict__ k1,
                                  const float* __restrict__ k2, const float* __restrict__ k3,
                                  const float* __restrict__ v0, const float* __restrict__ v1,
                                  const float* __restrict__ v2, const float* __restrict__ v3,
                                  float* __restrict__ outk, float* __restrict__ outv) {
    int lb = blockIdx.y;
    int l = lb >> 5;
    int b = lb & 31;
    const float* ks[4] = {k0, k1, k2, k3};
    const float* vs[4] = {v0, v1, v2, v3};
    const float* src = (blockIdx.z ? vs[l] : ks[l]) + (size_t)b * CACHE_T * NS;
    float* dst = (blockIdx.z ? outv : outk) + (size_t)(l * B + b) * SELF_T * NS;
    int i4 = blockIdx.x * 256 + threadIdx.x;
    if (i4 < (CACHE_T * NS) / 4) {
        ((float4*)dst)[i4] = ((const float4*)src)[i4];
    }
}

// LayerNorm over 384, one block (128 threads) per batch row; writes TRANSPOSED xlnT[d][b]
__global__ void ln_kernel(const float* __restrict__ x, const float* __restrict__ g,
                          const float* __restrict__ beta, float* __restrict__ xlnT) {
    int b = blockIdx.x;
    int tid = threadIdx.x;  // 128
    __shared__ float s_sum[128], s_sq[128];
    float v0 = x[b * NS + tid];
    float v1 = x[b * NS + tid + 128];
    float v2 = x[b * NS + tid + 256];
    s_sum[tid] = v0 + v1 + v2;
    s_sq[tid] = v0 * v0 + v1 * v1 + v2 * v2;
    __syncthreads();
    for (int off = 64; off > 0; off >>= 1) {
        if (tid < off) {
            s_sum[tid] += s_sum[tid + off];
            s_sq[tid] += s_sq[tid + off];
        }
        __syncthreads();
    }
    float m = s_sum[0] * (1.0f / NS);
    float var = s_sq[0] * (1.0f / NS) - m * m;
    float rs = rsqrtf(var + 1e-5f);
    xlnT[(tid)*B + b]       = (v0 - m) * rs * g[tid]       + beta[tid];
    xlnT[(tid + 128) * B + b] = (v1 - m) * rs * g[tid + 128] + beta[tid + 128];
    xlnT[(tid + 256) * B + b] = (v2 - m) * rs * g[tid + 256] + beta[tid + 256];
}

// y[b][n] = sum_d xT[d][b] * W[d][n] (+bias[n]) (+resid[b][n]) (gelu?) -> dst
// 256 threads: 64 n-lanes x 4 b-groups of 8. W read coalesced; xT via wave-uniform loads.
__global__ void gemv_kernel(const float* __restrict__ xT, const float* __restrict__ W,
                            const float* __restrict__ bias, const float* __restrict__ resid,
                            float* __restrict__ dst, int dst_stride, int D, int N,
                            int apply_gelu, int transpose_out) {
    int tid = threadIdx.x;
    int lane = tid & 63;
    int bg = __builtin_amdgcn_readfirstlane(tid >> 6);
    int n = blockIdx.x * 64 + lane;
    int b0 = bg * 8;
    float acc[8];
#pragma unroll
    for (int j = 0; j < 8; ++j) acc[j] = 0.f;
    const float* wp = W + n;
    const float* xp = xT + b0;
#pragma unroll 4
    for (int d = 0; d < D; ++d) {
        float w = wp[(size_t)d * N];
        const float* xr = xp + d * B;
#pragma unroll
        for (int j = 0; j < 8; ++j) acc[j] += xr[j] * w;
    }
    float bs = bias ? bias[n] : 0.f;
#pragma unroll
    for (int j = 0; j < 8; ++j) {
        float y = acc[j] + bs;
        if (resid) y += resid[(b0 + j) * NS + n];
        if (apply_gelu) y = 0.5f * y * (1.f + erff(y * 0.70710678118654752f));
        if (transpose_out) dst[(size_t)n * B + b0 + j] = y;
        else dst[(size_t)(b0 + j) * dst_stride + n] = y;
    }
}

// flash-decoding partial: one block per (b, h, split); chunk keys starting at split*chunk
__global__ void attn_partial_kernel(const float* __restrict__ q, const float* __restrict__ kbase,
                                    const float* __restrict__ vbase, int bstride, int chunk,
                                    float* __restrict__ po, float* __restrict__ pml) {
    int b = blockIdx.x, h = blockIdx.y, s = blockIdx.z;
    int tid = threadIdx.x;  // 256
    __shared__ __align__(16) float q_s[DH];
    __shared__ float sc[256];
    __shared__ float red[256];
    __shared__ float avred[4][DH];
    if (tid < DH) q_s[tid] = q[b * NS + h * DH + tid];
    __syncthreads();
    int k0 = s * chunk;
    const float* kp = kbase + (size_t)b * bstride + h * DH;

    // scores: 16 threads per key (4 floats each), 16 keys per iteration
    int kk = tid >> 4;
    int dq = (tid & 15) * 4;
    float4 qv = *(const float4*)(q_s + dq);
    for (int base = 0; base < chunk; base += 16) {
        int k = base + kk;
        float sv = 0.f;
        if (k < chunk) {
            float4 kv = *(const float4*)(kp + (size_t)(k0 + k) * NS + dq);
            sv = kv.x * qv.x + kv.y * qv.y + kv.z * qv.z + kv.w * qv.w;
        }
        sv += __shfl_xor(sv, 8);
        sv += __shfl_xor(sv, 4);
        sv += __shfl_xor(sv, 2);
        sv += __shfl_xor(sv, 1);
        if ((tid & 15) == 0 && k < chunk) sc[k] = sv * SCALE;
    }
    __syncthreads();

    // local max
    float mv = (tid < chunk) ? sc[tid] : -1e30f;
    red[tid] = mv;
    __syncthreads();
    for (int off = 128; off > 0; off >>= 1) {
        if (tid < off) red[tid] = fmaxf(red[tid], red[tid + off]);
        __syncthreads();
    }
    float m = red[0];
    __syncthreads();

    // exp + local sum
    float ps = 0.f;
    if (tid < chunk) {
        ps = expf(sc[tid] - m);
        sc[tid] = ps;
    }
    red[tid] = ps;
    __syncthreads();
    for (int off = 128; off > 0; off >>= 1) {
        if (tid < off) red[tid] += red[tid + off];
        __syncthreads();
    }
    float l = red[0];

    // AV: 4 key-groups x 64 dims
    int dh = tid & 63;
    int g = tid >> 6;
    const float* vp = vbase + (size_t)b * bstride + h * DH + dh;
    float acc = 0.f;
#pragma unroll 4
    for (int k = g; k < chunk; k += 4) {
        acc += sc[k] * vp[(size_t)(k0 + k) * NS];
    }
    avred[g][dh] = acc;
    __syncthreads();
    if (tid < DH) {
        float o = avred[0][tid] + avred[1][tid] + avred[2][tid] + avred[3][tid];
        int idx = (b * H + h) * 6 + s;
        po[(size_t)idx * DH + tid] = o;
        if (tid == 0) {
            pml[idx * 2 + 0] = m;
            pml[idx * 2 + 1] = l;
        }
    }
}

// combine S split partials -> oT[h*64+dh][b]
__global__ void attn_combine_kernel(const float* __restrict__ po, const float* __restrict__ pml,
                                    int S, float* __restrict__ oT) {
    int b = blockIdx.x, h = blockIdx.y;
    int tid = threadIdx.x;  // 64
    int base = (b * H + h) * 6;
    float M = -1e30f;
    for (int s = 0; s < S; ++s) M = fmaxf(M, pml[(base + s) * 2]);
    float L = 0.f, o = 0.f;
    for (int s = 0; s < S; ++s) {
        float w = expf(pml[(base + s) * 2] - M);
        L += pml[(base + s) * 2 + 1] * w;
        o += w * po[(size_t)(base + s) * DH + tid];
    }
    oT[(size_t)(h * DH + tid) * B + b] = o / L;
}

__global__ void addbias_kernel(float* __restrict__ x, const float* __restrict__ b2) {
    int b = blockIdx.x;
    int tid = threadIdx.x;  // 384
    x[b * NS + tid] += b2[tid];
}

// d-split partial of x += hT @ W2, atomicAdd into x. grid (6 n-tiles, 4 d-splits)
__global__ void mlp2_partial_kernel(const float* __restrict__ hT, const float* __restrict__ W2,
                                    float* __restrict__ x) {
    int tid = threadIdx.x;
    int lane = tid & 63;
    int bg = __builtin_amdgcn_readfirstlane(tid >> 6);
    int n = blockIdx.x * 64 + lane;
    int b0 = bg * 8;
    int d0 = blockIdx.y * 384;
    float acc[8];
#pragma unroll
    for (int j = 0; j < 8; ++j) acc[j] = 0.f;
    const float* wp = W2 + (size_t)d0 * NS + n;
    const float* xp = hT + (size_t)d0 * B + b0;
#pragma unroll 4
    for (int d = 0; d < 384; ++d) {
        float w = wp[(size_t)d * NS];
        const float* xr = xp + d * B;
#pragma unroll
        for (int j = 0; j < 8; ++j) acc[j] += xr[j] * w;
    }
#pragma unroll
    for (int j = 0; j < 8; ++j) atomicAdd(&x[(b0 + j) * NS + n], acc[j]);
}

// logits[b][v] = sum_d xT[d][b] * Wout[v][d]; one vocab row per thread, 32 batch accumulators
__global__ void logits_kernel(const float* __restrict__ xT, const float* __restrict__ Wout,
                              float* __restrict__ out) {
    int v = blockIdx.x * 256 + threadIdx.x;
    if (v >= VOCAB) return;
    float acc[32];
#pragma unroll
    for (int b = 0; b < 32; ++b) acc[b] = 0.f;
    const float4* wr = (const float4*)(Wout + (size_t)v * NS);
    for (int d4 = 0; d4 < NS / 4; ++d4) {
        float4 w = wr[d4];
        const float* x0 = xT + (size_t)(d4 * 4) * B;
#pragma unroll
        for (int b = 0; b < 32; ++b) {
            acc[b] += x0[b] * w.x + x0[b + B] * w.y + x0[b + 2 * B] * w.z + x0[b + 3 * B] * w.w;
        }
    }
#pragma unroll
    for (int b = 0; b < 32; ++b) out[(size_t)b * VOCAB + v] = acc[b];
}

extern "C" void kernel_launch(void* const* d_in, const int* in_sizes, int n_in,
                              void* d_out, int out_size, void* d_ws, size_t ws_size,
                              hipStream_t stream) {
    const float* te = (const float*)d_in[0];
    const float *crossk[4], *crossv[4], *selfk[4], *selfv[4];
    for (int i = 0; i < 4; ++i) {
        crossk[i] = (const float*)d_in[1 + 2 * i];
        crossv[i] = (const float*)d_in[2 + 2 * i];
        selfk[i] = (const float*)d_in[9 + 2 * i];
        selfv[i] = (const float*)d_in[10 + 2 * i];
    }
    const float* ln_g = (const float*)d_in[17];
    const float* ln_b = (const float*)d_in[18];
    const float* Wq = (const float*)d_in[19];
    const float* bq = (const float*)d_in[20];
    const float* Wk = (const float*)d_in[21];
    const float* Wv = (const float*)d_in[22];
    const float* bv = (const float*)d_in[23];
    const float* Wo = (const float*)d_in[24];
    const float* bo = (const float*)d_in[25];
    const float* cln_g = (const float*)d_in[26];
    const float* cln_b = (const float*)d_in[27];
    const float* cWq = (const float*)d_in[28];
    const float* cbq = (const float*)d_in[29];
    const float* cWo = (const float*)d_in[30];
    const float* cbo = (const float*)d_in[31];
    const float* mln_g = (const float*)d_in[32];
    const float* mln_b = (const float*)d_in[33];
    const float* W1 = (const float*)d_in[34];
    const float* b1 = (const float*)d_in[35];
    const float* W2 = (const float*)d_in[36];
    const float* b2 = (const float*)d_in[37];
    const float* lnf_g = (const float*)d_in[38];
    const float* lnf_b = (const float*)d_in[39];
    const float* Wout = (const float*)d_in[40];

    float* out = (float*)d_out;
    float* out_logits = out;
    float* out_ks = out + (size_t)B * VOCAB;
    float* out_vs = out_ks + (size_t)LAYERS * B * SELF_T * NS;

    float* ws = (float*)d_ws;
    float* xbuf = ws;
    float* xlnT = ws + 12288;
    float* qbuf = ws + 24576;
    float* oT = ws + 36864;
    float* h1T = ws + 49152;
    float* po = ws + 98304;
    float* pml = ws + 172032;

    copy_te_kernel<<<48, 256, 0, stream>>>(te, xbuf);
    copy_cache_kernel<<<dim3(168, 128, 2), 256, 0, stream>>>(
        selfk[0], selfk[1], selfk[2], selfk[3], selfv[0], selfv[1], selfv[2], selfv[3],
        out_ks, out_vs);

    for (int i = 0; i < LAYERS; ++i) {
        const float* Wq_i = Wq + (size_t)i * NS * NS;
        const float* Wk_i = Wk + (size_t)i * NS * NS;
        const float* Wv_i = Wv + (size_t)i * NS * NS;
        const float* Wo_i = Wo + (size_t)i * NS * NS;
        const float* cWq_i = cWq + (size_t)i * NS * NS;
        const float* cWo_i = cWo + (size_t)i * NS * NS;
        const float* W1_i = W1 + (size_t)i * NS * 4 * NS;
        const float* W2_i = W2 + (size_t)i * 4 * NS * NS;
        float* ks_l = out_ks + (size_t)i * B * SELF_T * NS;
        float* vs_l = out_vs + (size_t)i * B * SELF_T * NS;

        // --- self-attention block ---
        ln_kernel<<<32, 128, 0, stream>>>(xbuf, ln_g + i * NS, ln_b + i * NS, xlnT);
        gemv_kernel<<<6, 256, 0, stream>>>(xlnT, Wq_i, bq + i * NS, nullptr,
                                           qbuf, NS, NS, NS, 0, 0);
        gemv_kernel<<<6, 256, 0, stream>>>(xlnT, Wk_i, nullptr, nullptr,
                                           ks_l + (size_t)CACHE_T * NS, SELF_T * NS, NS, NS, 0, 0);
        gemv_kernel<<<6, 256, 0, stream>>>(xlnT, Wv_i, bv + i * NS, nullptr,
                                           vs_l + (size_t)CACHE_T * NS, SELF_T * NS, NS, NS, 0, 0);
        attn_partial_kernel<<<dim3(32, 6, 4), 256, 0, stream>>>(
            qbuf, ks_l, vs_l, SELF_T * NS, 112, po, pml);
        attn_combine_kernel<<<dim3(32, 6), 64, 0, stream>>>(po, pml, 4, oT);
        gemv_kernel<<<6, 256, 0, stream>>>(oT, Wo_i, bo + i * NS, xbuf, xbuf, NS, NS, NS, 0, 0);

        // --- cross-attention block ---
        ln_kernel<<<32, 128, 0, stream>>>(xbuf, cln_g + i * NS, cln_b + i * NS, xlnT);
        gemv_kernel<<<6, 256, 0, stream>>>(xlnT, cWq_i, cbq + i * NS, nullptr,
                                           qbuf, NS, NS, NS, 0, 0);
        attn_partial_kernel<<<dim3(32, 6, 6), 256, 0, stream>>>(
            qbuf, crossk[i], crossv[i], CROSS_T * NS, 250, po, pml);
        attn_combine_kernel<<<dim3(32, 6), 64, 0, stream>>>(po, pml, 6, oT);
        gemv_kernel<<<6, 256, 0, stream>>>(oT, cWo_i, cbo + i * NS, xbuf, xbuf, NS, NS, NS, 0, 0);

        // --- MLP block ---
        ln_kernel<<<32, 128, 0, stream>>>(xbuf, mln_g + i * NS, mln_b + i * NS, xlnT);
        gemv_kernel<<<24, 256, 0, stream>>>(xlnT, W1_i, b1 + i * 4 * NS, nullptr,
                                            h1T, 0, NS, 4 * NS, 1, 1);
        addbias_kernel<<<32, 384, 0, stream>>>(xbuf, b2 + i * NS);
        mlp2_partial_kernel<<<dim3(6, 4), 256, 0, stream>>>(h1T, W2_i, xbuf);
    }

    ln_kernel<<<32, 128, 0, stream>>>(xbuf, lnf_g, lnf_b, xlnT);
    logits_kernel<<<203, 256, 0, stream>>>(xlnT, Wout, out_logits);
}